// Round 12
// baseline (314.334 us; speedup 1.0000x reference)
//
#include <hip/hip_runtime.h>
#include <hip/hip_bf16.h>
#include <stdint.h>

// Problem constants
#define B_SZ 16384
#define D_SZ 1024
#define H1_SZ 512
#define H2_SZ 256
#define T_SZ 3
#define ESH 2
#define NE 8  // 2 shared + 3 tasks * 2 specific

typedef __bf16 bf16x8 __attribute__((ext_vector_type(8)));
typedef float f32x4 __attribute__((ext_vector_type(4)));
typedef unsigned short u16;
typedef u16 u16x8 __attribute__((ext_vector_type(8)));

__device__ __forceinline__ u16 f2bf(float f) {
  union { float f; uint32_t u; } v; v.f = f;
  uint32_t u = v.u;
  uint32_t r = (u + 0x7FFFu + ((u >> 16) & 1u)) >> 16;  // RNE
  return (u16)r;
}
__device__ __forceinline__ float bf2f(u16 b) {
  union { uint32_t u; float f; } v; v.u = ((uint32_t)b) << 16;
  return v.f;
}

__device__ __forceinline__ void gload16(const u16* src, u16* dst_lds) {
  __builtin_amdgcn_global_load_lds(
      (const __attribute__((address_space(1))) void*)src,
      (__attribute__((address_space(3))) void*)dst_lds, 16, 0, 0);
}

// ================= merged prep: gates+cast AND weight transposes =================
__global__ __launch_bounds__(256) void prep_kernel(
    const float* __restrict__ x, const float* __restrict__ gW,
    const float* __restrict__ gb, float* __restrict__ gates,
    u16* __restrict__ xb,
    const float* __restrict__ sW1, const float* __restrict__ pW1,
    const float* __restrict__ sW2, const float* __restrict__ pW2,
    u16* __restrict__ w1t, u16* __restrict__ w2t) {
  __shared__ __align__(16) float smem[12 * 1024];  // 48 KB
  const int tid = threadIdx.x;
  const int bid = blockIdx.x;

  if (bid < 4096) {
    float (*gw)[1024] = (float(*)[1024])smem;
    for (int i = tid; i < 12 * 1024; i += 256) {
      int tg = i >> 10, k = i & 1023;
      gw[tg][k] = gW[(size_t)(tg >> 2) * 4096 + (size_t)k * 4 + (tg & 3)];
    }
    __syncthreads();
    const int wid = tid >> 6, lane = tid & 63;
    const size_t b = (size_t)bid * 4 + wid;
    const float* xr = x + b * 1024;
    u16* xbr = xb + b * 1024;
    float acc[12] = {};
    for (int kk = 0; kk < 16; ++kk) {
      float xv = xr[kk * 64 + lane];
      xbr[kk * 64 + lane] = f2bf(xv);
#pragma unroll
      for (int t = 0; t < 12; ++t) acc[t] += xv * gw[t][kk * 64 + lane];
    }
#pragma unroll
    for (int off = 32; off >= 1; off >>= 1)
#pragma unroll
      for (int t = 0; t < 12; ++t) acc[t] += __shfl_xor(acc[t], off);
    if (lane == 0) {
      float* gr = gates + b * 12;
#pragma unroll
      for (int t = 0; t < 3; ++t) {
        float l0 = acc[t * 4 + 0] + gb[t * 4 + 0];
        float l1 = acc[t * 4 + 1] + gb[t * 4 + 1];
        float l2 = acc[t * 4 + 2] + gb[t * 4 + 2];
        float l3 = acc[t * 4 + 3] + gb[t * 4 + 3];
        float mx = fmaxf(fmaxf(l0, l1), fmaxf(l2, l3));
        float e0 = __expf(l0 - mx), e1 = __expf(l1 - mx);
        float e2 = __expf(l2 - mx), e3 = __expf(l3 - mx);
        float inv = 1.f / (e0 + e1 + e2 + e3);
        gr[t * 4 + 0] = e0 * inv; gr[t * 4 + 1] = e1 * inv;
        gr[t * 4 + 2] = e2 * inv; gr[t * 4 + 3] = e3 * inv;
      }
    }
  } else {
    float (*tile)[33] = (float(*)[33])smem;
    int K, N, n0, k0;
    const float* s;
    u16* d;
    if (bid < 8192) {
      const int t = bid - 4096;
      const int e = t >> 9, rem = t & 511;
      K = 1024; N = 512;
      n0 = (rem & 15) * 32; k0 = (rem >> 4) * 32;
      s = (e < 2) ? (sW1 + (size_t)e * K * N) : (pW1 + (size_t)(e - 2) * K * N);
      d = w1t + (size_t)e * K * N;
    } else {
      const int t = bid - 8192;
      const int e = t >> 7, rem = t & 127;
      K = 512; N = 256;
      n0 = (rem & 7) * 32; k0 = (rem >> 3) * 32;
      s = (e < 2) ? (sW2 + (size_t)e * K * N) : (pW2 + (size_t)(e - 2) * K * N);
      d = w2t + (size_t)e * K * N;
    }
    const int tx = tid & 31, ty = tid >> 5;
#pragma unroll
    for (int i = ty; i < 32; i += 8)
      tile[i][tx] = s[(size_t)(k0 + i) * N + n0 + tx];
    __syncthreads();
#pragma unroll
    for (int i = ty; i < 32; i += 8)
      d[(size_t)(n0 + i) * K + k0 + tx] = f2bf(tile[tx][i]);
  }
}

// ===== 128x128 MFMA GEMM, BK=32, 3-slot LDS ring, 3 blocks/CU =====
// Same proven ring3 schedule, narrowed to BN=128 so LDS ring = 48 KB ->
// THREE blocks/CU (3 independent 4-wave barrier domains, m114 overlap).
// 256 thr = 4 waves (1M x 4N), wave tile 128x32, acc[8][2] (64 AGPR).
// Stage 4 gloads/thread/tile; steady vmcnt(4); exact tail vmcnt(0)/none.
// T2 swizzle: 16B-slot s' = s ^ ((row>>1)&3) on BOTH stage-source and ds_read.
__global__ __launch_bounds__(256, 3) void gemm_ring3_128(
    const u16* __restrict__ A, size_t strideAe,
    const u16* __restrict__ Bt,
    const float* __restrict__ bias_sh, const float* __restrict__ bias_sp,
    u16* __restrict__ C, int M, int N, int K, int ntn_sh) {
  __shared__ __align__(16) u16 lds[3 * 8192];  // 48 KB
  const int tid = threadIdx.x;
  const int wid = tid >> 6, lane = tid & 63;
  const int fr = lane & 15, fq = lane >> 4;
  const int wc = wid;

  const int bid = blockIdx.x;
  const int e = bid & 7;
  const int r = bid >> 3;
  const int mtile = r >> ntn_sh;
  const int ntile = r & ((1 << ntn_sh) - 1);
  const int m0 = mtile * 128, n0 = ntile * 128;

  const u16* Ae = A + (size_t)e * strideAe;
  const u16* Be = Bt + (size_t)e * (size_t)N * K;
  const int NT = K >> 5;

  const u16* pA[2];
  const u16* pB[2];
#pragma unroll
  for (int p = 0; p < 2; ++p) {
    int c = p * 256 + tid, row = c >> 2, sl = (c & 3) ^ ((row >> 1) & 3);
    pA[p] = Ae + (size_t)(m0 + row) * K + sl * 8;
    pB[p] = Be + (size_t)(n0 + row) * K + sl * 8;
  }
  const int wdst = wid * 512;

  int offA[8], offB[2];
#pragma unroll
  for (int m = 0; m < 8; ++m) {
    int rr = m * 16 + fr;
    offA[m] = rr * 32 + ((fq ^ ((rr >> 1) & 3)) * 8);
  }
#pragma unroll
  for (int n = 0; n < 2; ++n) {
    int cg = wc * 32 + n * 16 + fr;
    offB[n] = 4096 + cg * 32 + ((fq ^ ((cg >> 1) & 3)) * 8);
  }

  f32x4 acc[8][2] = {};

#define STAGE(t, sb) do {                                             \
    gload16(pA[0] + (size_t)(t) * 32, &lds[(sb) + wdst]);             \
    gload16(pA[1] + (size_t)(t) * 32, &lds[(sb) + 2048 + wdst]);      \
    gload16(pB[0] + (size_t)(t) * 32, &lds[(sb) + 4096 + wdst]);      \
    gload16(pB[1] + (size_t)(t) * 32, &lds[(sb) + 6144 + wdst]); } while (0)

  STAGE(0, 0);
  STAGE(1, 8192);
  asm volatile("s_waitcnt vmcnt(4)");
  __builtin_amdgcn_s_barrier();
  __builtin_amdgcn_sched_barrier(0);

  int sb_cur = 0;
  for (int t = 0; t < NT; ++t) {
    const u16* sl = &lds[sb_cur];
    bf16x8 av[8], bv[2];
#pragma unroll
    for (int m = 0; m < 8; ++m) av[m] = *(const bf16x8*)&sl[offA[m]];
#pragma unroll
    for (int n = 0; n < 2; ++n) bv[n] = *(const bf16x8*)&sl[offB[n]];
    if (t + 2 < NT) {
      int sb_n2 = sb_cur + 2 * 8192;
      if (sb_n2 >= 24576) sb_n2 -= 24576;
      STAGE(t + 2, sb_n2);
    }
    __builtin_amdgcn_s_setprio(1);
#pragma unroll
    for (int m = 0; m < 8; ++m)
#pragma unroll
      for (int n = 0; n < 2; ++n)
        acc[m][n] = __builtin_amdgcn_mfma_f32_16x16x32_bf16(av[m], bv[n], acc[m][n], 0, 0, 0);
    __builtin_amdgcn_s_setprio(0);
    if (t + 2 < NT)      asm volatile("s_waitcnt vmcnt(4)");
    else if (t + 1 < NT) asm volatile("s_waitcnt vmcnt(0)");
    __builtin_amdgcn_s_barrier();
    __builtin_amdgcn_sched_barrier(0);
    sb_cur += 8192;
    if (sb_cur >= 24576) sb_cur = 0;
  }
#undef STAGE

  // ---- epilogue: bias+relu -> bf16, coalesced via LDS transpose (pad 136) ----
  const float* bias = (e < ESH) ? (bias_sh + (size_t)e * N)
                                : (bias_sp + (size_t)(e - ESH) * N);
  u16* Ce = C + (size_t)e * (size_t)M * N;
  float bb[2];
#pragma unroll
  for (int n = 0; n < 2; ++n) bb[n] = bias[n0 + wc * 32 + n * 16 + fr];

#pragma unroll
  for (int m = 0; m < 8; ++m) {
#pragma unroll
    for (int n = 0; n < 2; ++n) {
      const int col = wc * 32 + n * 16 + fr;
      f32x4 a = acc[m][n];
#pragma unroll
      for (int rr = 0; rr < 4; ++rr) {
        float v = a[rr] + bb[n];
        v = v > 0.f ? v : 0.f;
        lds[(m * 16 + fq * 4 + rr) * 136 + col] = f2bf(v);
      }
    }
  }
  __builtin_amdgcn_s_barrier();
  const int cc = (tid & 15) * 8;
  const int rr16 = tid >> 4;  // 0..15
#pragma unroll
  for (int pass = 0; pass < 8; ++pass) {
    const int lr = pass * 16 + rr16;  // 0..127
    u16x8 vv = *(const u16x8*)&lds[lr * 136 + cc];
    *(u16x8*)&Ce[(size_t)(m0 + lr) * N + n0 + cc] = vv;
  }
}

// ---------------- combine: out[b][t][h] = sum_g gate[b][t][g] * Y2[slot][b][h] ----------------
__global__ __launch_bounds__(256) void combine_kernel(
    const u16* __restrict__ y2, const float* __restrict__ gates,
    float* __restrict__ out) {
  const int tid = threadIdx.x;
  const int rb = tid >> 5;            // row within block (8 rows/block)
  const int hc = (tid & 31) * 8;      // h chunk of 8
  const size_t b = (size_t)blockIdx.x * 8 + rb;
  const float* g = gates + b * 12;
  float acc0[8] = {}, acc1[8] = {}, acc2[8] = {};
#pragma unroll
  for (int e = 0; e < 8; ++e) {
    u16x8 v = *(const u16x8*)&y2[(size_t)e * B_SZ * H2_SZ + b * H2_SZ + hc];
    float f[8];
#pragma unroll
    for (int i = 0; i < 8; ++i) f[i] = bf2f(v[i]);
    if (e < 2) {
      float g0 = g[0 * 4 + e], g1 = g[1 * 4 + e], g2 = g[2 * 4 + e];
#pragma unroll
      for (int i = 0; i < 8; ++i) {
        acc0[i] += g0 * f[i]; acc1[i] += g1 * f[i]; acc2[i] += g2 * f[i];
      }
    } else {
      const int t = (e - 2) >> 1, gi = 2 + ((e - 2) & 1);
      float gv = g[t * 4 + gi];
      float* acc = (t == 0) ? acc0 : (t == 1) ? acc1 : acc2;
#pragma unroll
      for (int i = 0; i < 8; ++i) acc[i] += gv * f[i];
    }
  }
  float* o = out + b * (3 * 256);
  *(float4*)&o[0 * 256 + hc]     = make_float4(acc0[0], acc0[1], acc0[2], acc0[3]);
  *(float4*)&o[0 * 256 + hc + 4] = make_float4(acc0[4], acc0[5], acc0[6], acc0[7]);
  *(float4*)&o[1 * 256 + hc]     = make_float4(acc1[0], acc1[1], acc1[2], acc1[3]);
  *(float4*)&o[1 * 256 + hc + 4] = make_float4(acc1[4], acc1[5], acc1[6], acc1[7]);
  *(float4*)&o[2 * 256 + hc]     = make_float4(acc2[0], acc2[1], acc2[2], acc2[3]);
  *(float4*)&o[2 * 256 + hc + 4] = make_float4(acc2[4], acc2[5], acc2[6], acc2[7]);
}

extern "C" void kernel_launch(void* const* d_in, const int* in_sizes, int n_in,
                              void* d_out, int out_size, void* d_ws, size_t ws_size,
                              hipStream_t stream) {
  (void)in_sizes; (void)n_in; (void)out_size; (void)ws_size;
  const float* x   = (const float*)d_in[0];
  const float* sW1 = (const float*)d_in[1];
  const float* sb1 = (const float*)d_in[2];
  const float* sW2 = (const float*)d_in[3];
  const float* sb2 = (const float*)d_in[4];
  const float* pW1 = (const float*)d_in[5];
  const float* pb1 = (const float*)d_in[6];
  const float* pW2 = (const float*)d_in[7];
  const float* pb2 = (const float*)d_in[8];
  const float* gW  = (const float*)d_in[9];
  const float* gb  = (const float*)d_in[10];

  uint8_t* ws = (uint8_t*)d_ws;
  u16* xb    = (u16*)(ws);                        // 33,554,432 B
  u16* w1t   = (u16*)(ws + 33554432);             //  8,388,608 B  [8][512][1024]
  u16* w2t   = (u16*)(ws + 41943040);             //  2,097,152 B  [8][256][512]
  u16* y1    = (u16*)(ws + 44040192);             // 134,217,728 B [8][B][512]
  u16* y2    = (u16*)(ws + 178257920);            // 67,108,864 B  [8][B][256]
  float* gts = (float*)(ws + 245366784);          //    786,432 B  [B][3][4]

  // 1) merged prep: gates+cast (bid<4096) + all weight transposes (bid 4096..9215)
  prep_kernel<<<9216, 256, 0, stream>>>(
      x, gW, gb, gts, xb, sW1, pW1, sW2, pW2, w1t, w2t);

  // 2) layer-1 GEMM: y1[e] = relu(xb @ w1t[e]^T + b1[e])   grid 128*4*8 = 4096
  gemm_ring3_128<<<(B_SZ / 128) * (512 / 128) * NE, 256, 0, stream>>>(
      xb, 0, w1t, sb1, pb1, y1, B_SZ, 512, 1024, 2);

  // 3) layer-2 GEMM: y2[e] = relu(y1[e] @ w2t[e]^T + b2[e])  grid 128*2*8 = 2048
  gemm_ring3_128<<<(B_SZ / 128) * (256 / 128) * NE, 256, 0, stream>>>(
      y1, (size_t)B_SZ * 512, w2t, sb2, pb2, y2, B_SZ, 256, 512, 1);

  // 4) combine with gates -> out [B][3][256] fp32
  combine_kernel<<<B_SZ / 8, 256, 0, stream>>>(y2, gts, (float*)d_out);
}

// Round 13
// 283.673 us; speedup vs baseline: 1.1081x; 1.1081x over previous
//
#include <hip/hip_runtime.h>
#include <hip/hip_bf16.h>
#include <stdint.h>

// Problem constants
#define B_SZ 16384
#define D_SZ 1024
#define H1_SZ 512
#define H2_SZ 256
#define T_SZ 3
#define ESH 2
#define NE 8  // 2 shared + 3 tasks * 2 specific

typedef __bf16 bf16x8 __attribute__((ext_vector_type(8)));
typedef float f32x4 __attribute__((ext_vector_type(4)));
typedef unsigned short u16;
typedef u16 u16x8 __attribute__((ext_vector_type(8)));

__device__ __forceinline__ u16 f2bf(float f) {
  union { float f; uint32_t u; } v; v.f = f;
  uint32_t u = v.u;
  uint32_t r = (u + 0x7FFFu + ((u >> 16) & 1u)) >> 16;  // RNE
  return (u16)r;
}
__device__ __forceinline__ float bf2f(u16 b) {
  union { uint32_t u; float f; } v; v.u = ((uint32_t)b) << 16;
  return v.f;
}

__device__ __forceinline__ void gload16(const u16* src, u16* dst_lds) {
  __builtin_amdgcn_global_load_lds(
      (const __attribute__((address_space(1))) void*)src,
      (__attribute__((address_space(3))) void*)dst_lds, 16, 0, 0);
}

// ------- merged transpose-cast: W1 jobs (z=0..7) and W2 jobs (z=8..15) -------
// [e][K][N] f32 -> [e][N][K] bf16
__global__ __launch_bounds__(256) void transpose_cast_all(
    const float* __restrict__ sW1, const float* __restrict__ pW1,
    const float* __restrict__ sW2, const float* __restrict__ pW2,
    u16* __restrict__ w1t, u16* __restrict__ w2t) {
  __shared__ float tile[32][33];
  const int z = blockIdx.z;
  int K, N;
  const float* s;
  u16* d;
  if (z < 8) {
    K = 1024; N = 512;
    s = (z < 2) ? (sW1 + (size_t)z * K * N) : (pW1 + (size_t)(z - 2) * K * N);
    d = w1t + (size_t)z * K * N;
  } else {
    K = 512; N = 256;
    const int e = z - 8;
    if (blockIdx.x >= 8 || blockIdx.y >= 16) return;
    s = (e < 2) ? (sW2 + (size_t)e * K * N) : (pW2 + (size_t)(e - 2) * K * N);
    d = w2t + (size_t)e * K * N;
  }
  int n0 = blockIdx.x * 32, k0 = blockIdx.y * 32;
  int tx = threadIdx.x, ty = threadIdx.y;
#pragma unroll
  for (int i = ty; i < 32; i += 8)
    tile[i][tx] = s[(size_t)(k0 + i) * N + n0 + tx];
  __syncthreads();
#pragma unroll
  for (int i = ty; i < 32; i += 8)
    d[(size_t)(n0 + i) * K + k0 + tx] = f2bf(tile[tx][i]);
}

// ---- gates + cast: gts = softmax(x @ gate_W + gate_b); xb = bf16(x) ----
__global__ __launch_bounds__(256) void gates_cast_kernel(
    const float* __restrict__ x, const float* __restrict__ gW,
    const float* __restrict__ gb, float* __restrict__ gates,
    u16* __restrict__ xb) {
  __shared__ float gw[12][1024];
  const int tid = threadIdx.x;
  for (int i = tid; i < 12 * 1024; i += 256) {
    int tg = i >> 10, k = i & 1023;
    gw[tg][k] = gW[(size_t)(tg >> 2) * 4096 + (size_t)k * 4 + (tg & 3)];
  }
  __syncthreads();
  const int wid = tid >> 6, lane = tid & 63;
  const size_t b = (size_t)blockIdx.x * 4 + wid;
  const float* xr = x + b * 1024;
  u16* xbr = xb + b * 1024;
  float acc[12] = {};
  for (int kk = 0; kk < 16; ++kk) {
    float xv = xr[kk * 64 + lane];
    xbr[kk * 64 + lane] = f2bf(xv);
#pragma unroll
    for (int t = 0; t < 12; ++t) acc[t] += xv * gw[t][kk * 64 + lane];
  }
#pragma unroll
  for (int off = 32; off >= 1; off >>= 1)
#pragma unroll
    for (int t = 0; t < 12; ++t) acc[t] += __shfl_xor(acc[t], off);
  if (lane == 0) {
    float* gr = gates + b * 12;
#pragma unroll
    for (int t = 0; t < 3; ++t) {
      float l0 = acc[t * 4 + 0] + gb[t * 4 + 0];
      float l1 = acc[t * 4 + 1] + gb[t * 4 + 1];
      float l2 = acc[t * 4 + 2] + gb[t * 4 + 2];
      float l3 = acc[t * 4 + 3] + gb[t * 4 + 3];
      float mx = fmaxf(fmaxf(l0, l1), fmaxf(l2, l3));
      float e0 = __expf(l0 - mx), e1 = __expf(l1 - mx);
      float e2 = __expf(l2 - mx), e3 = __expf(l3 - mx);
      float inv = 1.f / (e0 + e1 + e2 + e3);
      gr[t * 4 + 0] = e0 * inv; gr[t * 4 + 1] = e1 * inv;
      gr[t * 4 + 2] = e2 * inv; gr[t * 4 + 3] = e3 * inv;
    }
  }
}

// ===== 128x256 MFMA GEMM, BK=32, 3-slot LDS ring, 2 blocks/CU (measured best) =====
// C[e] = relu(A[e] @ Bt[e]^T + bias[e]),  A:[M][K] bf16, Bt:[e][N][K] bf16.
// 256 threads = 4 waves (1M x 4N), per-wave 128x64 output, acc[8][4] (128 AGPR).
// LDS: 3 slots x 24KB = 72KB -> 2 blocks/CU; two independent 4-wave barrier
// domains per CU (m114 overlap). Stage tile t+2 during t; steady vmcnt(6);
// exact tail: t=NT-2 -> vmcnt(0), t=NT-1 -> none.
// T2 swizzle: 16B-slot s' = s ^ ((row>>1)&3) on BOTH stage-source and ds_read.
__global__ __launch_bounds__(256, 2) void gemm_ring3(
    const u16* __restrict__ A, size_t strideAe,
    const u16* __restrict__ Bt,
    const float* __restrict__ bias_sh, const float* __restrict__ bias_sp,
    u16* __restrict__ C, int M, int N, int K, int ntn_sh) {
  __shared__ __align__(16) u16 lds[3 * 12288];  // 72 KB
  const int tid = threadIdx.x;
  const int wid = tid >> 6, lane = tid & 63;
  const int fr = lane & 15, fq = lane >> 4;
  const int wc = wid;

  const int bid = blockIdx.x;
  const int e = bid & 7;
  const int r = bid >> 3;
  const int mtile = r >> ntn_sh;
  const int ntile = r & ((1 << ntn_sh) - 1);
  const int m0 = mtile * 128, n0 = ntile * 256;

  const u16* Ae = A + (size_t)e * strideAe;
  const u16* Be = Bt + (size_t)e * (size_t)N * K;
  const int NT = K >> 5;

  const u16* pA[2];
  const u16* pB[4];
#pragma unroll
  for (int p = 0; p < 2; ++p) {
    int c = p * 256 + tid, row = c >> 2, sl = (c & 3) ^ ((row >> 1) & 3);
    pA[p] = Ae + (size_t)(m0 + row) * K + sl * 8;
  }
#pragma unroll
  for (int p = 0; p < 4; ++p) {
    int c = p * 256 + tid, row = c >> 2, sl = (c & 3) ^ ((row >> 1) & 3);
    pB[p] = Be + (size_t)(n0 + row) * K + sl * 8;
  }
  const int wdst = wid * 512;

  int offA[8], offB[4];
#pragma unroll
  for (int m = 0; m < 8; ++m) {
    int rr = m * 16 + fr;
    offA[m] = rr * 32 + ((fq ^ ((rr >> 1) & 3)) * 8);
  }
#pragma unroll
  for (int n = 0; n < 4; ++n) {
    int cg = wc * 64 + n * 16 + fr;
    offB[n] = 4096 + cg * 32 + ((fq ^ ((cg >> 1) & 3)) * 8);
  }

  f32x4 acc[8][4] = {};

#define STAGE(t, sb) do {                                             \
    gload16(pA[0] + (size_t)(t) * 32, &lds[(sb) + wdst]);             \
    gload16(pA[1] + (size_t)(t) * 32, &lds[(sb) + 2048 + wdst]);      \
    gload16(pB[0] + (size_t)(t) * 32, &lds[(sb) + 4096 + wdst]);      \
    gload16(pB[1] + (size_t)(t) * 32, &lds[(sb) + 6144 + wdst]);      \
    gload16(pB[2] + (size_t)(t) * 32, &lds[(sb) + 8192 + wdst]);      \
    gload16(pB[3] + (size_t)(t) * 32, &lds[(sb) + 10240 + wdst]); } while (0)

  STAGE(0, 0);
  STAGE(1, 12288);
  asm volatile("s_waitcnt vmcnt(6)");
  __builtin_amdgcn_s_barrier();
  __builtin_amdgcn_sched_barrier(0);

  int sb_cur = 0;
  for (int t = 0; t < NT; ++t) {
    const u16* sl = &lds[sb_cur];
    bf16x8 av[8], bv[4];
#pragma unroll
    for (int m = 0; m < 8; ++m) av[m] = *(const bf16x8*)&sl[offA[m]];
#pragma unroll
    for (int n = 0; n < 4; ++n) bv[n] = *(const bf16x8*)&sl[offB[n]];
    if (t + 2 < NT) {
      int sb_n2 = sb_cur + 2 * 12288;
      if (sb_n2 >= 36864) sb_n2 -= 36864;
      STAGE(t + 2, sb_n2);
    }
    __builtin_amdgcn_s_setprio(1);
#pragma unroll
    for (int m = 0; m < 8; ++m)
#pragma unroll
      for (int n = 0; n < 4; ++n)
        acc[m][n] = __builtin_amdgcn_mfma_f32_16x16x32_bf16(av[m], bv[n], acc[m][n], 0, 0, 0);
    __builtin_amdgcn_s_setprio(0);
    if (t + 2 < NT)      asm volatile("s_waitcnt vmcnt(6)");
    else if (t + 1 < NT) asm volatile("s_waitcnt vmcnt(0)");
    __builtin_amdgcn_s_barrier();
    __builtin_amdgcn_sched_barrier(0);
    sb_cur += 12288;
    if (sb_cur >= 36864) sb_cur = 0;
  }
#undef STAGE

  const float* bias = (e < ESH) ? (bias_sh + (size_t)e * N)
                                : (bias_sp + (size_t)(e - ESH) * N);
  u16* Ce = C + (size_t)e * (size_t)M * N;
  float bb[4];
#pragma unroll
  for (int n = 0; n < 4; ++n) bb[n] = bias[n0 + wc * 64 + n * 16 + fr];

#pragma unroll
  for (int m = 0; m < 8; ++m) {
#pragma unroll
    for (int n = 0; n < 4; ++n) {
      const int col = wc * 64 + n * 16 + fr;
      f32x4 a = acc[m][n];
#pragma unroll
      for (int rr = 0; rr < 4; ++rr) {
        float v = a[rr] + bb[n];
        v = v > 0.f ? v : 0.f;
        lds[(m * 16 + fq * 4 + rr) * 264 + col] = f2bf(v);
      }
    }
  }
  __builtin_amdgcn_s_barrier();
  const int cc = (tid & 31) * 8;
  const int rr8 = tid >> 5;
#pragma unroll
  for (int pass = 0; pass < 16; ++pass) {
    const int lr = pass * 8 + rr8;
    u16x8 vv = *(const u16x8*)&lds[lr * 264 + cc];
    *(u16x8*)&Ce[(size_t)(m0 + lr) * N + n0 + cc] = vv;
  }
}

// ---------------- combine: out[b][t][h] = sum_g gate[b][t][g] * Y2[slot][b][h] ----------------
__global__ __launch_bounds__(256) void combine_kernel(
    const u16* __restrict__ y2, const float* __restrict__ gates,
    float* __restrict__ out) {
  const int tid = threadIdx.x;
  const int rb = tid >> 5;            // row within block (8 rows/block)
  const int hc = (tid & 31) * 8;      // h chunk of 8
  const size_t b = (size_t)blockIdx.x * 8 + rb;
  const float* g = gates + b * 12;
  float acc0[8] = {}, acc1[8] = {}, acc2[8] = {};
#pragma unroll
  for (int e = 0; e < 8; ++e) {
    u16x8 v = *(const u16x8*)&y2[(size_t)e * B_SZ * H2_SZ + b * H2_SZ + hc];
    float f[8];
#pragma unroll
    for (int i = 0; i < 8; ++i) f[i] = bf2f(v[i]);
    if (e < 2) {
      float g0 = g[0 * 4 + e], g1 = g[1 * 4 + e], g2 = g[2 * 4 + e];
#pragma unroll
      for (int i = 0; i < 8; ++i) {
        acc0[i] += g0 * f[i]; acc1[i] += g1 * f[i]; acc2[i] += g2 * f[i];
      }
    } else {
      const int t = (e - 2) >> 1, gi = 2 + ((e - 2) & 1);
      float gv = g[t * 4 + gi];
      float* acc = (t == 0) ? acc0 : (t == 1) ? acc1 : acc2;
#pragma unroll
      for (int i = 0; i < 8; ++i) acc[i] += gv * f[i];
    }
  }
  float* o = out + b * (3 * 256);
  *(float4*)&o[0 * 256 + hc]     = make_float4(acc0[0], acc0[1], acc0[2], acc0[3]);
  *(float4*)&o[0 * 256 + hc + 4] = make_float4(acc0[4], acc0[5], acc0[6], acc0[7]);
  *(float4*)&o[1 * 256 + hc]     = make_float4(acc1[0], acc1[1], acc1[2], acc1[3]);
  *(float4*)&o[1 * 256 + hc + 4] = make_float4(acc1[4], acc1[5], acc1[6], acc1[7]);
  *(float4*)&o[2 * 256 + hc]     = make_float4(acc2[0], acc2[1], acc2[2], acc2[3]);
  *(float4*)&o[2 * 256 + hc + 4] = make_float4(acc2[4], acc2[5], acc2[6], acc2[7]);
}

extern "C" void kernel_launch(void* const* d_in, const int* in_sizes, int n_in,
                              void* d_out, int out_size, void* d_ws, size_t ws_size,
                              hipStream_t stream) {
  (void)in_sizes; (void)n_in; (void)out_size; (void)ws_size;
  const float* x   = (const float*)d_in[0];
  const float* sW1 = (const float*)d_in[1];
  const float* sb1 = (const float*)d_in[2];
  const float* sW2 = (const float*)d_in[3];
  const float* sb2 = (const float*)d_in[4];
  const float* pW1 = (const float*)d_in[5];
  const float* pb1 = (const float*)d_in[6];
  const float* pW2 = (const float*)d_in[7];
  const float* pb2 = (const float*)d_in[8];
  const float* gW  = (const float*)d_in[9];
  const float* gb  = (const float*)d_in[10];

  uint8_t* ws = (uint8_t*)d_ws;
  u16* xb    = (u16*)(ws);                        // 33,554,432 B
  u16* w1t   = (u16*)(ws + 33554432);             //  8,388,608 B  [8][512][1024]
  u16* w2t   = (u16*)(ws + 41943040);             //  2,097,152 B  [8][256][512]
  u16* y1    = (u16*)(ws + 44040192);             // 134,217,728 B [8][B][512]
  u16* y2    = (u16*)(ws + 178257920);            // 67,108,864 B  [8][B][256]
  float* gts = (float*)(ws + 245366784);          //    786,432 B  [B][3][4]

  // 1) all weight transposes in one launch (W1: z=0..7, W2: z=8..15)
  transpose_cast_all<<<dim3(16, 32, 16), dim3(32, 8), 0, stream>>>(
      sW1, pW1, sW2, pW2, w1t, w2t);

  // 2) gates + x-cast fused
  gates_cast_kernel<<<B_SZ / 4, 256, 0, stream>>>(x, gW, gb, gts, xb);

  // 3) layer-1 GEMM: y1[e] = relu(xb @ w1t[e]^T + b1[e])   grid 128*2*8 = 2048
  gemm_ring3<<<(B_SZ / 128) * (512 / 256) * NE, 256, 0, stream>>>(
      xb, 0, w1t, sb1, pb1, y1, B_SZ, 512, 1024, 1);

  // 4) layer-2 GEMM: y2[e] = relu(y1[e] @ w2t[e]^T + b2[e])  grid 128*1*8 = 1024
  gemm_ring3<<<(B_SZ / 128) * (256 / 128) * NE / 2, 256, 0, stream>>>(
      y1, (size_t)B_SZ * 512, w2t, sb2, pb2, y2, B_SZ, 256, 512, 0);

  // 5) combine with gates -> out [B][3][256] fp32
  combine_kernel<<<B_SZ / 8, 256, 0, stream>>>(y2, gts, (float*)d_out);
}